// Round 6
// baseline (474.042 us; speedup 1.0000x reference)
//
#include <hip/hip_runtime.h>

// Geometry fixed by the reference.
constexpr int Dd  = 96;
constexpr int Hh  = 160;
constexpr int Ww  = 160;
constexpr int HW  = Hh * Ww;       // 25600
constexpr int DHW = Dd * HW;       // 2,457,600

// remap: normalize(/(s-1)) + grid_sample(align_corners=False) collapse to
//   sample = (voxel + disp) * s/(s-1) - 0.5
constexpr float KZ = 96.0f / 95.0f;
constexpr float KY = 160.0f / 159.0f;
constexpr float KX = 160.0f / 159.0f;

// ---------------- compose kernels: tile (z,y,x) = 4 x 8 x 16 ----------------
// Staged window per axis: base = floor((o-2)*k - 0.5), size = T + 6 (covers
// all corners for |disp| < 2; rarer lanes take the global fallback).
constexpr int C_TZ = 4, C_TY = 8, C_TX = 16;
constexpr int C_SZ = 10, C_SY = 14, C_SX = 22;          // staged dims
constexpr int C_CELLS = C_SZ * C_SY * C_SX;             // 3080 (49.3 KB f4)
constexpr int C_NTX = Ww / C_TX;                        // 10
constexpr int C_NTY = Hh / C_TY;                        // 20
constexpr int C_NTZ = Dd / C_TZ;                        // 24
constexpr int C_NBLK = C_NTX * C_NTY * C_NTZ;           // 4800
constexpr int C_CHUNK = C_NBLK / 8;                     // 600 (XCD swizzle)

// ---------------- fused kernel: tile (z,y,x) = 2 x 8 x 16 -------------------
constexpr int F_TZ = 2, F_TY = 8, F_TX = 16;
constexpr int F_SZ = 8,  F_SY = 14, F_SX = 22;          // compose window
constexpr int F_CELLS = F_SZ * F_SY * F_SX;             // 2464 (39.4 KB f4)
constexpr int S_SZ = 12, S_SY = 18, S_SX = 26;          // src window (halo 4)
constexpr int S_CELLS = S_SZ * S_SY * S_SX;             // 5616 (22.5 KB f32)
constexpr int F_NTX = Ww / F_TX;                        // 10
constexpr int F_NTY = Hh / F_TY;                        // 20
constexpr int F_NTZ = Dd / F_TZ;                        // 48
constexpr int F_NBLK = F_NTX * F_NTY * F_NTZ;           // 9600
constexpr int F_CHUNK = F_NBLK / 8;                     // 1200

__device__ __forceinline__ int iclamp(int v, int lo, int hi) {
    return min(max(v, lo), hi);
}

// Per-axis floor + validity-folded weights: w0/w1 are zero when the corner
// falls outside the volume (zeros padding), so corner weight = wz*wy*wx.
struct Ax { int i0; float w0, w1; };
__device__ __forceinline__ Ax axis_setup(float s, int n) {
    float f = floorf(s);
    int i0 = (int)f;
    float t = s - f;
    Ax a;
    a.i0 = i0;
    a.w0 = (i0 >= 0 && i0 < n) ? 1.0f - t : 0.0f;
    a.w1 = (i0 + 1 >= 0 && i0 + 1 < n) ? t : 0.0f;
    return a;
}

// ============================ compose ======================================
// out4 = trilinear_sample(source, voxel + dvf*rf) + dvf   (interleaved out)
// PLANAR_SRC: source given as 3 planar float planes (first stage, f0);
// otherwise as interleaved float4 (intermediates).
template <bool PLANAR_SRC>
__global__ __launch_bounds__(256) void compose_lds(
        const float4* __restrict__ src4,   // [DHW] interleaved (if !PLANAR_SRC)
        const float*  __restrict__ srcp,   // [3,DHW] planar    (if PLANAR_SRC)
        const float*  __restrict__ dvf,    // [3,DHW] planar
        const float*  __restrict__ rf_ptr,
        float4* __restrict__ out4)         // [DHW] interleaved
{
    __shared__ float4 sm[C_CELLS];

    // XCD swizzle: each XCD gets a contiguous run of tiles (12 z-slices).
    int s = (blockIdx.x & 7) * C_CHUNK + (blockIdx.x >> 3);
    int tx = s % C_NTX; int t2 = s / C_NTX;
    int ty = t2 % C_NTY; int tz = t2 / C_NTY;
    int ox = tx * C_TX, oy = ty * C_TY, oz = tz * C_TZ;

    int bx = (int)floorf((float)(ox - 2) * KX - 0.5f);
    int by = (int)floorf((float)(oy - 2) * KY - 0.5f);
    int bz = (int)floorf((float)(oz - 2) * KZ - 0.5f);

    // Stage window (clamped at volume edges -> consistent with corner clamp).
    for (int c = threadIdx.x; c < C_CELLS; c += 256) {
        int lx = c % C_SX; int tt = c / C_SX;
        int ly = tt % C_SY; int lz = tt / C_SY;
        int gx = iclamp(bx + lx, 0, Ww - 1);
        int gy = iclamp(by + ly, 0, Hh - 1);
        int gz = iclamp(bz + lz, 0, Dd - 1);
        int g = gz * HW + gy * Ww + gx;
        if (PLANAR_SRC)
            sm[c] = make_float4(srcp[g], srcp[DHW + g], srcp[2 * DHW + g], 0.0f);
        else
            sm[c] = src4[g];
    }
    __syncthreads();

    float rf = *rf_ptr;
    int vx  = ox + (threadIdx.x & 15);
    int vy  = oy + ((threadIdx.x >> 4) & 7);
    int vz0 = oz + (threadIdx.x >> 7);

#pragma unroll
    for (int rep = 0; rep < 2; ++rep) {
        int vz = vz0 + rep * 2;
        int idx = vz * HW + vy * Ww + vx;

        float fd = dvf[idx];
        float fh = dvf[DHW + idx];
        float fw = dvf[2 * DHW + idx];

        Ax az = axis_setup(((float)vz + fd * rf) * KZ - 0.5f, Dd);
        Ax ay = axis_setup(((float)vy + fh * rf) * KY - 0.5f, Hh);
        Ax ax = axis_setup(((float)vx + fw * rf) * KX - 0.5f, Ww);

        float wz[2] = {az.w0, az.w1};
        float wy[2] = {ay.w0, ay.w1};
        float wx[2] = {ax.w0, ax.w1};

        int lz = az.i0 - bz, ly = ay.i0 - by, lx = ax.i0 - bx;
        bool ok = (unsigned)lz <= (unsigned)(C_SZ - 2) &&
                  (unsigned)ly <= (unsigned)(C_SY - 2) &&
                  (unsigned)lx <= (unsigned)(C_SX - 2);

        float a0 = 0.0f, a1 = 0.0f, a2 = 0.0f;
        if (ok) {
#pragma unroll
            for (int dz = 0; dz < 2; ++dz)
#pragma unroll
                for (int dy = 0; dy < 2; ++dy)
#pragma unroll
                    for (int dx = 0; dx < 2; ++dx) {
                        float wk = wz[dz] * wy[dy] * wx[dx];
                        float4 v = sm[((lz + dz) * C_SY + (ly + dy)) * C_SX + lx + dx];
                        a0 += wk * v.x; a1 += wk * v.y; a2 += wk * v.z;
                    }
        } else {  // rare straggler: exact global gather with clamped coords
            int cz[2] = {iclamp(az.i0, 0, Dd - 1), iclamp(az.i0 + 1, 0, Dd - 1)};
            int cy[2] = {iclamp(ay.i0, 0, Hh - 1), iclamp(ay.i0 + 1, 0, Hh - 1)};
            int cx[2] = {iclamp(ax.i0, 0, Ww - 1), iclamp(ax.i0 + 1, 0, Ww - 1)};
#pragma unroll
            for (int dz = 0; dz < 2; ++dz)
#pragma unroll
                for (int dy = 0; dy < 2; ++dy)
#pragma unroll
                    for (int dx = 0; dx < 2; ++dx) {
                        float wk = wz[dz] * wy[dy] * wx[dx];
                        int g = cz[dz] * HW + cy[dy] * Ww + cx[dx];
                        if (PLANAR_SRC) {
                            a0 += wk * srcp[g];
                            a1 += wk * srcp[DHW + g];
                            a2 += wk * srcp[2 * DHW + g];
                        } else {
                            float4 v = src4[g];
                            a0 += wk * v.x; a1 += wk * v.y; a2 += wk * v.z;
                        }
                    }
        }
        out4[idx] = make_float4(a0 + fd, a1 + fh, a2 + fw, 0.0f);
    }
}

// ============================ fused final ==================================
//   composed3 = sample(composed2, voxel + final*rf) + final -> out_flow (planar)
//   out_img   = sample(src, voxel + composed3*rf)
__global__ __launch_bounds__(256) void final_fused_lds(
        const float4* __restrict__ composed2, // [DHW] interleaved
        const float*  __restrict__ fflow,     // [3,DHW] planar
        const float*  __restrict__ src,       // [DHW]
        const float*  __restrict__ rf_ptr,
        float* __restrict__ out_flow,         // [3,DHW] planar
        float* __restrict__ out_img)          // [DHW]
{
    __shared__ float4 smc[F_CELLS];
    __shared__ float  sms[S_CELLS];

    int s = (blockIdx.x & 7) * F_CHUNK + (blockIdx.x >> 3);
    int tx = s % F_NTX; int t2 = s / F_NTX;
    int ty = t2 % F_NTY; int tz = t2 / F_NTY;
    int ox = tx * F_TX, oy = ty * F_TY, oz = tz * F_TZ;

    // compose window (halo 2)
    int bx = (int)floorf((float)(ox - 2) * KX - 0.5f);
    int by = (int)floorf((float)(oy - 2) * KY - 0.5f);
    int bz = (int)floorf((float)(oz - 2) * KZ - 0.5f);
    // src window (halo 4)
    int b2x = (int)floorf((float)(ox - 4) * KX - 0.5f);
    int b2y = (int)floorf((float)(oy - 4) * KY - 0.5f);
    int b2z = (int)floorf((float)(oz - 4) * KZ - 0.5f);

    for (int c = threadIdx.x; c < F_CELLS; c += 256) {
        int lx = c % F_SX; int tt = c / F_SX;
        int ly = tt % F_SY; int lz = tt / F_SY;
        int gx = iclamp(bx + lx, 0, Ww - 1);
        int gy = iclamp(by + ly, 0, Hh - 1);
        int gz = iclamp(bz + lz, 0, Dd - 1);
        smc[c] = composed2[gz * HW + gy * Ww + gx];
    }
    for (int c = threadIdx.x; c < S_CELLS; c += 256) {
        int lx = c % S_SX; int tt = c / S_SX;
        int ly = tt % S_SY; int lz = tt / S_SY;
        int gx = iclamp(b2x + lx, 0, Ww - 1);
        int gy = iclamp(b2y + ly, 0, Hh - 1);
        int gz = iclamp(b2z + lz, 0, Dd - 1);
        sms[c] = src[gz * HW + gy * Ww + gx];
    }
    __syncthreads();

    float rf = *rf_ptr;
    int vx = ox + (threadIdx.x & 15);
    int vy = oy + ((threadIdx.x >> 4) & 7);
    int vz = oz + (threadIdx.x >> 7);
    int idx = vz * HW + vy * Ww + vx;

    float fd = fflow[idx];
    float fh = fflow[DHW + idx];
    float fw = fflow[2 * DHW + idx];

    // --- gather composed2 ---
    Ax az = axis_setup(((float)vz + fd * rf) * KZ - 0.5f, Dd);
    Ax ay = axis_setup(((float)vy + fh * rf) * KY - 0.5f, Hh);
    Ax ax = axis_setup(((float)vx + fw * rf) * KX - 0.5f, Ww);
    float wz[2] = {az.w0, az.w1};
    float wy[2] = {ay.w0, ay.w1};
    float wx[2] = {ax.w0, ax.w1};

    int lz = az.i0 - bz, ly = ay.i0 - by, lx = ax.i0 - bx;
    bool ok = (unsigned)lz <= (unsigned)(F_SZ - 2) &&
              (unsigned)ly <= (unsigned)(F_SY - 2) &&
              (unsigned)lx <= (unsigned)(F_SX - 2);

    float a0 = 0.0f, a1 = 0.0f, a2 = 0.0f;
    if (ok) {
#pragma unroll
        for (int dz = 0; dz < 2; ++dz)
#pragma unroll
            for (int dy = 0; dy < 2; ++dy)
#pragma unroll
                for (int dx = 0; dx < 2; ++dx) {
                    float wk = wz[dz] * wy[dy] * wx[dx];
                    float4 v = smc[((lz + dz) * F_SY + (ly + dy)) * F_SX + lx + dx];
                    a0 += wk * v.x; a1 += wk * v.y; a2 += wk * v.z;
                }
    } else {
        int cz[2] = {iclamp(az.i0, 0, Dd - 1), iclamp(az.i0 + 1, 0, Dd - 1)};
        int cy[2] = {iclamp(ay.i0, 0, Hh - 1), iclamp(ay.i0 + 1, 0, Hh - 1)};
        int cx[2] = {iclamp(ax.i0, 0, Ww - 1), iclamp(ax.i0 + 1, 0, Ww - 1)};
#pragma unroll
        for (int dz = 0; dz < 2; ++dz)
#pragma unroll
            for (int dy = 0; dy < 2; ++dy)
#pragma unroll
                for (int dx = 0; dx < 2; ++dx) {
                    float wk = wz[dz] * wy[dy] * wx[dx];
                    float4 v = composed2[cz[dz] * HW + cy[dy] * Ww + cx[dx]];
                    a0 += wk * v.x; a1 += wk * v.y; a2 += wk * v.z;
                }
    }
    float c0 = a0 + fd, c1 = a1 + fh, c2 = a2 + fw;   // composed3
    out_flow[idx]           = c0;
    out_flow[DHW + idx]     = c1;
    out_flow[2 * DHW + idx] = c2;

    // --- gather src at voxel + composed3*rf ---
    Ax sz_ = axis_setup(((float)vz + c0 * rf) * KZ - 0.5f, Dd);
    Ax sy_ = axis_setup(((float)vy + c1 * rf) * KY - 0.5f, Hh);
    Ax sx_ = axis_setup(((float)vx + c2 * rf) * KX - 0.5f, Ww);
    float uz[2] = {sz_.w0, sz_.w1};
    float uy[2] = {sy_.w0, sy_.w1};
    float ux[2] = {sx_.w0, sx_.w1};

    int mz = sz_.i0 - b2z, my = sy_.i0 - b2y, mx = sx_.i0 - b2x;
    bool ok2 = (unsigned)mz <= (unsigned)(S_SZ - 2) &&
               (unsigned)my <= (unsigned)(S_SY - 2) &&
               (unsigned)mx <= (unsigned)(S_SX - 2);

    float acc = 0.0f;
    if (ok2) {
#pragma unroll
        for (int dz = 0; dz < 2; ++dz)
#pragma unroll
            for (int dy = 0; dy < 2; ++dy)
#pragma unroll
                for (int dx = 0; dx < 2; ++dx) {
                    float wk = uz[dz] * uy[dy] * ux[dx];
                    acc += wk * sms[((mz + dz) * S_SY + (my + dy)) * S_SX + mx + dx];
                }
    } else {
        int cz[2] = {iclamp(sz_.i0, 0, Dd - 1), iclamp(sz_.i0 + 1, 0, Dd - 1)};
        int cy[2] = {iclamp(sy_.i0, 0, Hh - 1), iclamp(sy_.i0 + 1, 0, Hh - 1)};
        int cx[2] = {iclamp(sx_.i0, 0, Ww - 1), iclamp(sx_.i0 + 1, 0, Ww - 1)};
#pragma unroll
        for (int dz = 0; dz < 2; ++dz)
#pragma unroll
            for (int dy = 0; dy < 2; ++dy)
#pragma unroll
                for (int dx = 0; dx < 2; ++dx) {
                    float wk = uz[dz] * uy[dy] * ux[dx];
                    acc += wk * src[cz[dz] * HW + cy[dy] * Ww + cx[dx]];
                }
    }
    out_img[idx] = acc;
}

extern "C" void kernel_launch(void* const* d_in, const int* in_sizes, int n_in,
                              void* d_out, int out_size, void* d_ws, size_t ws_size,
                              hipStream_t stream) {
    const float* src        = (const float*)d_in[0];   // [1,1,D,H,W]
    const float* flow_list  = (const float*)d_in[1];   // [3,1,3,D,H,W]
    const float* final_flow = (const float*)d_in[2];   // [1,3,D,H,W]
    const float* rf         = (const float*)d_in[3];   // scalar

    float* out_img  = (float*)d_out;          // deform_2_img: [DHW]
    float* out_flow = (float*)d_out + DHW;    // out_flow (== composed3): [3,DHW]

    float4* bufA = (float4*)d_ws;             // [DHW] interleaved
    float4* bufB = bufA + DHW;                // [DHW] interleaved

    const float* f0 = flow_list;
    const float* f1 = flow_list + 3 * (size_t)DHW;
    const float* f2 = flow_list + 6 * (size_t)DHW;

    dim3 block(256);

    // bufB = composed1 = warp(f0, grid(f1)) + f1   (planar source)
    compose_lds<true><<<dim3(C_NBLK), block, 0, stream>>>(nullptr, f0, f1, rf, bufB);
    // bufA = composed2 = warp(composed1, grid(f2)) + f2
    compose_lds<false><<<dim3(C_NBLK), block, 0, stream>>>(bufB, nullptr, f2, rf, bufA);
    // out_flow = composed3 ; out_img = warp(src, grid(composed3))
    final_fused_lds<<<dim3(F_NBLK), block, 0, stream>>>(bufA, final_flow, src, rf,
                                                        out_flow, out_img);
}

// Round 10
// 249.031 us; speedup vs baseline: 1.9035x; 1.9035x over previous
//
#include <hip/hip_runtime.h>

// Geometry fixed by the reference.
constexpr int Dd  = 96;
constexpr int Hh  = 160;
constexpr int Ww  = 160;
constexpr int HW  = Hh * Ww;       // 25600
constexpr int DHW = Dd * HW;       // 2,457,600

constexpr int NBLK  = DHW / 256;   // 9600
constexpr int CHUNK = NBLK / 8;    // 1200 (XCD z-chunk swizzle, bijective)

// remap: normalize(/(s-1)) + grid_sample(align_corners=False) collapse to
//   sample = (voxel + disp*rf) * s/(s-1) - 0.5
constexpr float KZ = 96.0f / 95.0f;
constexpr float KY = 160.0f / 159.0f;
constexpr float KX = 160.0f / 159.0f;

__device__ __forceinline__ int iclamp(int v, int lo, int hi) {
    return min(max(v, lo), hi);
}

// bf16 <-> f32 (RNE)
__device__ __forceinline__ float bf2f(unsigned short u) {
    return __uint_as_float(((unsigned)u) << 16);
}
__device__ __forceinline__ unsigned short f2bf(float f) {
    unsigned u = __float_as_uint(f);
    return (unsigned short)((u + 0x7FFFu + ((u >> 16) & 1u)) >> 16);
}

// Per-axis floor + validity-folded weights (zeros padding -> weight zeroed
// when corner out of bounds; index clamped so loads stay in-range).
struct Ax { int i0; float w0, w1; };
__device__ __forceinline__ Ax axis_setup(float s, int n) {
    float f = floorf(s);
    int i0 = (int)f;
    float t = s - f;
    Ax a;
    a.i0 = i0;
    a.w0 = (i0 >= 0 && i0 < n) ? 1.0f - t : 0.0f;
    a.w1 = (i0 + 1 >= 0 && i0 + 1 < n) ? t : 0.0f;
    return a;
}

// Pack planar [3,DHW] f32 flow -> [DHW] ushort4 bf16 (w unused). 4 voxels/thread.
__global__ __launch_bounds__(256) void pack_bf16(
        const float* __restrict__ f, ushort4* __restrict__ out)
{
    int i = blockIdx.x * blockDim.x + threadIdx.x;    // group of 4 voxels
    const float4* p0 = (const float4*)f;
    const float4* p1 = (const float4*)(f + DHW);
    const float4* p2 = (const float4*)(f + 2 * DHW);
    float4 a = p0[i], b = p1[i], c = p2[i];
    ushort4 o;
    o = make_ushort4(f2bf(a.x), f2bf(b.x), f2bf(c.x), 0); out[4 * i + 0] = o;
    o = make_ushort4(f2bf(a.y), f2bf(b.y), f2bf(c.y), 0); out[4 * i + 1] = o;
    o = make_ushort4(f2bf(a.z), f2bf(b.z), f2bf(c.z), 0); out[4 * i + 2] = o;
    o = make_ushort4(f2bf(a.w), f2bf(b.w), f2bf(c.w), 0); out[4 * i + 3] = o;
}

// out = trilinear_sample(src_bf16, voxel + dvf*rf) + dvf      (bf16x4 out)
__global__ __launch_bounds__(256) void compose_bf(
        const ushort4* __restrict__ src,      // [DHW] bf16x4 (d,h,w,_)
        const float*   __restrict__ dvf,      // [3,DHW] planar f32
        const float*   __restrict__ rf_ptr,
        ushort4* __restrict__ out)            // [DHW] bf16x4
{
    int b = (blockIdx.x & 7) * CHUNK + (blockIdx.x >> 3);
    int idx = b * 256 + threadIdx.x;
    float rf = *rf_ptr;

    int d = idx / HW;
    int rem = idx - d * HW;
    int h = rem / Ww;
    int w = rem - h * Ww;

    float fd = dvf[idx];
    float fh = dvf[DHW + idx];
    float fw = dvf[2 * DHW + idx];

    Ax az = axis_setup(((float)d + fd * rf) * KZ - 0.5f, Dd);
    Ax ay = axis_setup(((float)h + fh * rf) * KY - 0.5f, Hh);
    Ax ax = axis_setup(((float)w + fw * rf) * KX - 0.5f, Ww);

    float wz[2] = {az.w0, az.w1};
    float wy[2] = {ay.w0, ay.w1};
    float wx[2] = {ax.w0, ax.w1};
    int cz[2] = {iclamp(az.i0, 0, Dd - 1) * HW, iclamp(az.i0 + 1, 0, Dd - 1) * HW};
    int cy[2] = {iclamp(ay.i0, 0, Hh - 1) * Ww, iclamp(ay.i0 + 1, 0, Hh - 1) * Ww};
    int cx[2] = {iclamp(ax.i0, 0, Ww - 1),      iclamp(ax.i0 + 1, 0, Ww - 1)};

    float a0 = 0.0f, a1 = 0.0f, a2 = 0.0f;
#pragma unroll
    for (int dz = 0; dz < 2; ++dz)
#pragma unroll
        for (int dy = 0; dy < 2; ++dy)
#pragma unroll
            for (int dx = 0; dx < 2; ++dx) {
                float wk = wz[dz] * wy[dy] * wx[dx];
                ushort4 v = src[cz[dz] + cy[dy] + cx[dx]];
                a0 += wk * bf2f(v.x);
                a1 += wk * bf2f(v.y);
                a2 += wk * bf2f(v.z);
            }
    out[idx] = make_ushort4(f2bf(a0 + fd), f2bf(a1 + fh), f2bf(a2 + fw), 0);
}

// Fused stages 3+4:
//   composed3 = sample(composed2_bf16, voxel + final*rf) + final -> out_flow (f32 planar)
//   out_img   = sample(src_f32, voxel + composed3*rf)
__global__ __launch_bounds__(256) void final_fused(
        const ushort4* __restrict__ composed2, // [DHW] bf16x4
        const float*   __restrict__ fflow,     // [3,DHW] planar f32
        const float*   __restrict__ src,       // [DHW] f32
        const float*   __restrict__ rf_ptr,
        float* __restrict__ out_flow,          // [3,DHW] planar f32
        float* __restrict__ out_img)           // [DHW] f32
{
    int b = (blockIdx.x & 7) * CHUNK + (blockIdx.x >> 3);
    int idx = b * 256 + threadIdx.x;
    float rf = *rf_ptr;

    int d = idx / HW;
    int rem = idx - d * HW;
    int h = rem / Ww;
    int w = rem - h * Ww;

    float fd = fflow[idx];
    float fh = fflow[DHW + idx];
    float fw = fflow[2 * DHW + idx];

    // --- gather composed2 (bf16x4) ---
    Ax az = axis_setup(((float)d + fd * rf) * KZ - 0.5f, Dd);
    Ax ay = axis_setup(((float)h + fh * rf) * KY - 0.5f, Hh);
    Ax ax = axis_setup(((float)w + fw * rf) * KX - 0.5f, Ww);
    float wz[2] = {az.w0, az.w1};
    float wy[2] = {ay.w0, ay.w1};
    float wx[2] = {ax.w0, ax.w1};
    int cz[2] = {iclamp(az.i0, 0, Dd - 1) * HW, iclamp(az.i0 + 1, 0, Dd - 1) * HW};
    int cy[2] = {iclamp(ay.i0, 0, Hh - 1) * Ww, iclamp(ay.i0 + 1, 0, Hh - 1) * Ww};
    int cx[2] = {iclamp(ax.i0, 0, Ww - 1),      iclamp(ax.i0 + 1, 0, Ww - 1)};

    float a0 = 0.0f, a1 = 0.0f, a2 = 0.0f;
#pragma unroll
    for (int dz = 0; dz < 2; ++dz)
#pragma unroll
        for (int dy = 0; dy < 2; ++dy)
#pragma unroll
            for (int dx = 0; dx < 2; ++dx) {
                float wk = wz[dz] * wy[dy] * wx[dx];
                ushort4 v = composed2[cz[dz] + cy[dy] + cx[dx]];
                a0 += wk * bf2f(v.x);
                a1 += wk * bf2f(v.y);
                a2 += wk * bf2f(v.z);
            }
    float c0 = a0 + fd, c1 = a1 + fh, c2 = a2 + fw;   // composed3 (f32)
    out_flow[idx]           = c0;
    out_flow[DHW + idx]     = c1;
    out_flow[2 * DHW + idx] = c2;

    // --- gather src (f32) at voxel + composed3*rf ---
    Ax sz_ = axis_setup(((float)d + c0 * rf) * KZ - 0.5f, Dd);
    Ax sy_ = axis_setup(((float)h + c1 * rf) * KY - 0.5f, Hh);
    Ax sx_ = axis_setup(((float)w + c2 * rf) * KX - 0.5f, Ww);
    float uz[2] = {sz_.w0, sz_.w1};
    float uy[2] = {sy_.w0, sy_.w1};
    float ux[2] = {sx_.w0, sx_.w1};
    int ez[2] = {iclamp(sz_.i0, 0, Dd - 1) * HW, iclamp(sz_.i0 + 1, 0, Dd - 1) * HW};
    int ey[2] = {iclamp(sy_.i0, 0, Hh - 1) * Ww, iclamp(sy_.i0 + 1, 0, Hh - 1) * Ww};
    int ex[2] = {iclamp(sx_.i0, 0, Ww - 1),      iclamp(sx_.i0 + 1, 0, Ww - 1)};

    float acc = 0.0f;
#pragma unroll
    for (int dz = 0; dz < 2; ++dz)
#pragma unroll
        for (int dy = 0; dy < 2; ++dy)
#pragma unroll
            for (int dx = 0; dx < 2; ++dx) {
                float wk = uz[dz] * uy[dy] * ux[dx];
                acc += wk * src[ez[dz] + ey[dy] + ex[dx]];
            }
    out_img[idx] = acc;
}

extern "C" void kernel_launch(void* const* d_in, const int* in_sizes, int n_in,
                              void* d_out, int out_size, void* d_ws, size_t ws_size,
                              hipStream_t stream) {
    const float* src        = (const float*)d_in[0];   // [1,1,D,H,W]
    const float* flow_list  = (const float*)d_in[1];   // [3,1,3,D,H,W]
    const float* final_flow = (const float*)d_in[2];   // [1,3,D,H,W]
    const float* rf         = (const float*)d_in[3];   // scalar

    float* out_img  = (float*)d_out;          // deform_2_img: [DHW]
    float* out_flow = (float*)d_out + DHW;    // out_flow (== composed3): [3,DHW]

    ushort4* bufA = (ushort4*)d_ws;           // [DHW] bf16x4
    ushort4* bufB = bufA + DHW;               // [DHW] bf16x4
    ushort4* bufC = bufB + DHW;               // [DHW] bf16x4 (f0 packed)

    const float* f0 = flow_list;
    const float* f1 = flow_list + 3 * (size_t)DHW;
    const float* f2 = flow_list + 6 * (size_t)DHW;

    dim3 block(256);

    // bufC = bf16-packed f0   (streaming)
    pack_bf16<<<dim3(DHW / 4 / 256), block, 0, stream>>>(f0, bufC);
    // bufB = composed1 = warp(f0, grid(f1)) + f1
    compose_bf<<<dim3(NBLK), block, 0, stream>>>(bufC, f1, rf, bufB);
    // bufA = composed2 = warp(composed1, grid(f2)) + f2
    compose_bf<<<dim3(NBLK), block, 0, stream>>>(bufB, f2, rf, bufA);
    // out_flow = composed3 ; out_img = warp(src, grid(composed3))
    final_fused<<<dim3(NBLK), block, 0, stream>>>(bufA, final_flow, src, rf,
                                                  out_flow, out_img);
}